// Round 1
// baseline (441.241 us; speedup 1.0000x reference)
//
#include <hip/hip_runtime.h>

// Cross product along dim=1 of (16, 3, 1024, 1024) fp32 tensors.
// Layout (row-major): idx = ((b*3 + c)*1024 + h)*1024 + w.
// Component stride = P = 1024*1024 floats; batch stride = 3*P.
// Memory-bound: 604 MB total traffic, roofline ~96 us at 6.3 TB/s.

#define P4 (1024 * 1024 / 4)   // float4 elements per component plane (262144, pow2)

__global__ __launch_bounds__(256) void cross_kernel(
    const float4* __restrict__ a,
    const float4* __restrict__ b,
    float4* __restrict__ out,
    int n4)   // total float4 positions = 16 * P4
{
    int i = blockIdx.x * blockDim.x + threadIdx.x;
    if (i >= n4) return;

    int batch = i >> 18;          // i / P4
    int r     = i & (P4 - 1);     // i % P4
    long base = (long)batch * (3 * P4) + r;

    float4 a0 = a[base];
    float4 a1 = a[base + P4];
    float4 a2 = a[base + 2 * P4];
    float4 b0 = b[base];
    float4 b1 = b[base + P4];
    float4 b2 = b[base + 2 * P4];

    float4 c0, c1, c2;
#define CROSS_LANE(F)                          \
    c0.F = a1.F * b2.F - a2.F * b1.F;          \
    c1.F = a2.F * b0.F - a0.F * b2.F;          \
    c2.F = a0.F * b1.F - a1.F * b0.F;
    CROSS_LANE(x)
    CROSS_LANE(y)
    CROSS_LANE(z)
    CROSS_LANE(w)
#undef CROSS_LANE

    out[base]          = c0;
    out[base + P4]     = c1;
    out[base + 2 * P4] = c2;
}

extern "C" void kernel_launch(void* const* d_in, const int* in_sizes, int n_in,
                              void* d_out, int out_size, void* d_ws, size_t ws_size,
                              hipStream_t stream) {
    const float4* a = (const float4*)d_in[0];
    const float4* b = (const float4*)d_in[1];
    float4* out = (float4*)d_out;

    // out_size = 16*3*1024*1024 floats; positions (b,h,w) = out_size/3; /4 for float4
    int n4 = out_size / 3 / 4;   // 4,194,304
    int block = 256;
    int grid = (n4 + block - 1) / block;   // 16384
    cross_kernel<<<grid, block, 0, stream>>>(a, b, out, n4);
}